// Round 17
// baseline (531.715 us; speedup 1.0000x reference)
//
#include <hip/hip_runtime.h>
#include <cstddef>
#include <cstdint>

#define DIMC   768
#define HEADS  12
#define HD     64
#define BATCH  8
#define SEQ    4096
#define MTOK   (BATCH*SEQ)     // 32768
#define THREEC (3*DIMC)        // 2304
#define BHN    (BATCH*HEADS)   // 96
#define NCHUNK 8               // token chunks per (b,h)
#define CHTOK  (SEQ/NCHUNK)    // 512 tokens per chunk
#define EPSN   1e-12f
#define KT     (DIMC/32)       // 24 k-tiles
#define TILE_U16 1024          // one (16-row x 32-k) tile: hi 512 + lo 512 u16
#define ROWTILE_U16 (KT*TILE_U16)  // 24576 u16 per 16-row block

typedef unsigned short u16;
typedef unsigned int   u32;
typedef __attribute__((ext_vector_type(8))) short short8;   // 8 bf16 (4 VGPR)
typedef __attribute__((ext_vector_type(4))) float f32x4;

__device__ inline u16 bf16_rne(float f) {
  u32 u = __float_as_uint(f);
  u32 r = u + 0x7fffu + ((u >> 16) & 1u);
  return (u16)(r >> 16);
}

// packed f32x2 -> bf16x2 (low16 = cvt(a), high16 = cvt(b)); gfx950 HW RNE
__device__ inline u32 cvt_pk_bf16(float a, float b) {
  u32 r;
  asm("v_cvt_pk_bf16_f32 %0, %1, %2" : "=v"(r) : "v"(a), "v"(b));
  return r;
}

// ---------------------------------------------------------------------------
// Split fp32 [R][768] row-major -> bf16 hi/lo in MFMA-FRAGMENT-TILE order.
// ---------------------------------------------------------------------------
__global__ __launch_bounds__(256)
void split_tiles(const float* __restrict__ in, u16* __restrict__ outp,
                 int nrowtiles) {
  const int l = threadIdx.x & 63;
  const int ntiles = nrowtiles * KT;
  for (int gw = (blockIdx.x * 256 + threadIdx.x) >> 6; gw < ntiles;
       gw += (gridDim.x * 256) >> 6) {
    const int rt = gw / KT, kt = gw % KT;
    const float* src = in + (size_t)(rt * 16 + (l & 15)) * DIMC + kt * 32 + (l >> 4) * 8;
    float4 x0 = *(const float4*)src;
    float4 x1 = *(const float4*)(src + 4);
    float xs[8] = {x0.x, x0.y, x0.z, x0.w, x1.x, x1.y, x1.z, x1.w};
    u32 hw[4], lw[4];
    #pragma unroll
    for (int i = 0; i < 4; ++i) {
      u16 h0 = bf16_rne(xs[2*i]);
      u16 h1 = bf16_rne(xs[2*i+1]);
      float r0 = xs[2*i]   - __uint_as_float(((u32)h0) << 16);
      float r1 = xs[2*i+1] - __uint_as_float(((u32)h1) << 16);
      u16 l0 = bf16_rne(r0);
      u16 l1 = bf16_rne(r1);
      hw[i] = (u32)h0 | ((u32)h1 << 16);
      lw[i] = (u32)l0 | ((u32)l1 << 16);
    }
    u16* tb = outp + (size_t)gw * TILE_U16;
    *(uint4*)(tb + l * 8)       = make_uint4(hw[0], hw[1], hw[2], hw[3]);
    *(uint4*)(tb + 512 + l * 8) = make_uint4(lw[0], lw[1], lw[2], lw[3]);
  }
}

// ---------------------------------------------------------------------------
// Transposed split: source element (row rr, k kk) = in[kk*ld + rr].
// ---------------------------------------------------------------------------
__global__ __launch_bounds__(256)
void split_tiles_t(const float* __restrict__ in, u16* __restrict__ outp,
                   int nrowtiles, int ld) {
  const int l = threadIdx.x & 63;
  const int ntiles = nrowtiles * KT;
  for (int gw = (blockIdx.x * 256 + threadIdx.x) >> 6; gw < ntiles;
       gw += (gridDim.x * 256) >> 6) {
    const int rt = gw / KT, kt = gw % KT;
    const int m = rt * 16 + (l & 15);
    const int k0 = kt * 32 + (l >> 4) * 8;
    float xs[8];
    #pragma unroll
    for (int j = 0; j < 8; ++j) xs[j] = in[(size_t)(k0 + j) * ld + m];
    u32 hw[4], lw[4];
    #pragma unroll
    for (int i = 0; i < 4; ++i) {
      u16 h0 = bf16_rne(xs[2*i]);
      u16 h1 = bf16_rne(xs[2*i+1]);
      float r0 = xs[2*i]   - __uint_as_float(((u32)h0) << 16);
      float r1 = xs[2*i+1] - __uint_as_float(((u32)h1) << 16);
      u16 l0 = bf16_rne(r0);
      u16 l1 = bf16_rne(r1);
      hw[i] = (u32)h0 | ((u32)h1 << 16);
      lw[i] = (u32)l0 | ((u32)l1 << 16);
    }
    u16* tb = outp + (size_t)gw * TILE_U16;
    *(uint4*)(tb + l * 8)       = make_uint4(hw[0], hw[1], hw[2], hw[3]);
    *(uint4*)(tb + 512 + l * 8) = make_uint4(lw[0], lw[1], lw[2], lw[3]);
  }
}

// ---------------------------------------------------------------------------
// Stage 1: qkv GEMM (MFMA bf16x3) + |q|,|k| sums + MFMA kv outer product.
// A double-buffered through LDS (R15 structure); B-fragments SOFTWARE-
// PIPELINED 1 kt ahead into registers (B was loaded just-before-use -> wave
// stalled on L2/L3 latency every kt; 3 waves/SIMD only cover ~525 cyc).
// unroll 2 keeps the kt&1 buffer indices compile-time-static (no scratch).
// ---------------------------------------------------------------------------
__global__ __launch_bounds__(256, 3)
void qkv_stage1(const u16* __restrict__ xc, const u16* __restrict__ wc,
                float* __restrict__ kvp, float* __restrict__ dqp,
                float* __restrict__ dkp) {
  const int bid = blockIdx.x;
  const int h = bid % HEADS;
  const int bc = bid / HEADS;
  const int b = bc >> 3, chunk = bc & 7;
  const int bh = b * HEADS + h;
  const int si = bh * NCHUNK + chunk;

  const int tid = threadIdx.x;
  const int w = tid >> 6, l = tid & 63;
  const int lr16 = l & 15, cg = l >> 4;

  __shared__ __align__(16) unsigned char smem[33792];
  u16* lds16 = (u16*)smem;   // kt loop: A-dbuf 2x4096 u16 at [0,8192)
                             // scatter: k^T tiles [0,8192), v tiles [8192,16384)
  float* red = (float*)smem; // epilogue scratch

  f32x4 kvacc[4] = {(f32x4){0,0,0,0},(f32x4){0,0,0,0},(f32x4){0,0,0,0},(f32x4){0,0,0,0}};
  float dsum_q = 0.f, dsum_k = 0.f;

  // B-frag bases: section ot (q/k/v), rows ot*DIMC + h*64 + w*16 .. +16
  const u16* wbase[3];
  #pragma unroll
  for (int ot = 0; ot < 3; ++ot) {
    const int grow = ot * DIMC + h * HD + w * 16;
    wbase[ot] = wc + (size_t)(grow >> 4) * ROWTILE_U16 + (l << 3);
  }
  const int atile0 = (b * SEQ + chunk * CHTOK) >> 4;

  for (int sub = 0; sub < 8; ++sub) {
    const u16* asub = xc + (size_t)(atile0 + sub * 4) * ROWTILE_U16;
    const u16* gw0 = asub + (size_t)w * ROWTILE_U16 + (l << 3);
    __syncthreads();   // prev sub's kv-MFMA reads done -> LDS reusable
    // prologue: stage A tile kt=0 into buf0; preload B[0] into registers
    {
      uint4 a0 = *(const uint4*)gw0;
      uint4 a1 = *(const uint4*)(gw0 + 512);
      *(uint4*)(lds16 + w * 1024 + (l << 3))       = a0;
      *(uint4*)(lds16 + w * 1024 + 512 + (l << 3)) = a1;
    }
    short8 bc_h[3], bc_l[3];
    #pragma unroll
    for (int ot = 0; ot < 3; ++ot) {
      bc_h[ot] = *(const short8*)(wbase[ot]);
      bc_l[ot] = *(const short8*)(wbase[ot] + 512);
    }
    __syncthreads();

    f32x4 acc[4][3];
    #pragma unroll
    for (int tt = 0; tt < 4; ++tt)
      #pragma unroll
      for (int ot = 0; ot < 3; ++ot)
        acc[tt][ot] = (f32x4){0.f, 0.f, 0.f, 0.f};

    #pragma unroll 2
    for (int kt = 0; kt < KT; ++kt) {
      const int cur = (kt & 1) << 12;          // A buffer offset (u16)
      const int nxt = cur ^ 4096;
      // issue next-kt A stage loads + B prefetch EARLY (latency hides
      // under the 36 MFMAs below)
      uint4 s0, s1;
      short8 bn_h[3], bn_l[3];
      if (kt + 1 < KT) {
        const u16* g = gw0 + (kt + 1) * TILE_U16;
        s0 = *(const uint4*)g;
        s1 = *(const uint4*)(g + 512);
        const int noff = (kt + 1) * TILE_U16;
        #pragma unroll
        for (int ot = 0; ot < 3; ++ot) {
          bn_h[ot] = *(const short8*)(wbase[ot] + noff);
          bn_l[ot] = *(const short8*)(wbase[ot] + noff + 512);
        }
      }
      // compute kt from LDS A + registered B
      #pragma unroll
      for (int tt = 0; tt < 4; ++tt) {
        short8 ah = *(const short8*)(lds16 + cur + tt * 1024 + (l << 3));
        short8 al = *(const short8*)(lds16 + cur + tt * 1024 + 512 + (l << 3));
        #pragma unroll
        for (int ot = 0; ot < 3; ++ot) {
          acc[tt][ot] = __builtin_amdgcn_mfma_f32_16x16x32_bf16(ah, bc_h[ot], acc[tt][ot], 0, 0, 0);
          acc[tt][ot] = __builtin_amdgcn_mfma_f32_16x16x32_bf16(ah, bc_l[ot], acc[tt][ot], 0, 0, 0);
          acc[tt][ot] = __builtin_amdgcn_mfma_f32_16x16x32_bf16(al, bc_h[ot], acc[tt][ot], 0, 0, 0);
        }
      }
      if (kt + 1 < KT) {
        *(uint4*)(lds16 + nxt + w * 1024 + (l << 3))       = s0;
        *(uint4*)(lds16 + nxt + w * 1024 + 512 + (l << 3)) = s1;
        #pragma unroll
        for (int ot = 0; ot < 3; ++ot) {
          bc_h[ot] = bn_h[ot];
          bc_l[ot] = bn_l[ot];
        }
      }
      __syncthreads();
    }
    // --- scatter phase (kt loop's trailing barrier protects A-dbuf readers)
    #pragma unroll
    for (int tt = 0; tt < 4; ++tt) {
      dsum_q += fabsf(acc[tt][0][0]);
      dsum_q += fabsf(acc[tt][0][1]);
      dsum_q += fabsf(acc[tt][0][2]);
      dsum_q += fabsf(acc[tt][0][3]);
    }
    #pragma unroll
    for (int sec = 1; sec < 3; ++sec) {
      const int region = (sec == 1) ? 0 : 8192;
      #pragma unroll
      for (int tt = 0; tt < 4; ++tt) {
        const float v0 = acc[tt][sec][0], v1 = acc[tt][sec][1];
        const float v2 = acc[tt][sec][2], v3 = acc[tt][sec][3];
        if (sec == 1) {
          dsum_k += fabsf(v0);
          dsum_k += fabsf(v1);
          dsum_k += fabsf(v2);
          dsum_k += fabsf(v3);
        }
        const u32 ph01 = cvt_pk_bf16(v0, v1);
        const u32 ph23 = cvt_pk_bf16(v2, v3);
        const float r0 = v0 - __uint_as_float(ph01 << 16);
        const float r1 = v1 - __uint_as_float(ph01 & 0xffff0000u);
        const float r2 = v2 - __uint_as_float(ph23 << 16);
        const float r3 = v3 - __uint_as_float(ph23 & 0xffff0000u);
        const u32 pl01 = cvt_pk_bf16(r0, r1);
        const u32 pl23 = cvt_pk_bf16(r2, r3);
        const int pos = region + (w * 2 + (tt >> 1)) * TILE_U16 +
                        ((lr16 | (((tt * 2 + (cg >> 1)) & 3) << 4)) << 3) +
                        ((cg & 1) << 2);
        *(uint2*)(lds16 + pos)       = make_uint2(ph01, ph23);
        *(uint2*)(lds16 + pos + 512) = make_uint2(pl01, pl23);
      }
    }
    __syncthreads();
    // kv MFMA: wave w owns d-tile w (rows w*16..+16), all 4 e-tiles, K=64
    {
      const u16* At = lds16 + w * 2 * TILE_U16;
      const u16* Bt = lds16 + 8192;
      #pragma unroll
      for (int t2 = 0; t2 < 2; ++t2) {
        short8 kah = *(const short8*)(At + t2 * TILE_U16 + (l << 3));
        short8 kal = *(const short8*)(At + t2 * TILE_U16 + 512 + (l << 3));
        #pragma unroll
        for (int et = 0; et < 4; ++et) {
          short8 vbh = *(const short8*)(Bt + (et * 2 + t2) * TILE_U16 + (l << 3));
          short8 vbl = *(const short8*)(Bt + (et * 2 + t2) * TILE_U16 + 512 + (l << 3));
          kvacc[et] = __builtin_amdgcn_mfma_f32_16x16x32_bf16(kah, vbh, kvacc[et], 0, 0, 0);
          kvacc[et] = __builtin_amdgcn_mfma_f32_16x16x32_bf16(kah, vbl, kvacc[et], 0, 0, 0);
          kvacc[et] = __builtin_amdgcn_mfma_f32_16x16x32_bf16(kal, vbh, kvacc[et], 0, 0, 0);
        }
      }
    }
  }
  // write kv partial: d = w*16 + cg*4 + r, e = et*16 + lr16
  float* ob = kvp + (size_t)si * (HD * HD);
  #pragma unroll
  for (int et = 0; et < 4; ++et)
    #pragma unroll
    for (int r = 0; r < 4; ++r)
      ob[(w * 16 + cg * 4 + r) * HD + et * 16 + lr16] = kvacc[et][r];
  // dq/dk reduction: red_q[64][4] @0, red_k[64][4] @256 (one writer per slot)
  __syncthreads();
  red[(w * 16 + lr16) * 4 + cg]       = dsum_q;
  red[256 + (w * 16 + lr16) * 4 + cg] = dsum_k;
  __syncthreads();
  if (tid < 64) {
    dqp[(size_t)si * HD + tid] = red[tid*4] + red[tid*4+1] + red[tid*4+2] + red[tid*4+3];
  } else if (tid < 128) {
    const int d = tid - 64;
    dkp[(size_t)si * HD + d] = red[256 + d*4] + red[256 + d*4+1] + red[256 + d*4+2] + red[256 + d*4+3];
  }
}

// ---------------------------------------------------------------------------
__global__ __launch_bounds__(256)
void kv_reduce(const float* __restrict__ kvp, const float* __restrict__ dqp,
               const float* __restrict__ dkp, float* __restrict__ kvs) {
  const int bh = blockIdx.x;
  const int tid = threadIdx.x;
  __shared__ float dqL[64], dkL[64];
  if (tid < 64) {
    float s = 0.f;
    #pragma unroll
    for (int c = 0; c < NCHUNK; ++c) s += dqp[((size_t)bh * NCHUNK + c) * HD + tid];
    dqL[tid] = fmaxf(s, EPSN);
  } else if (tid < 128) {
    const int d = tid - 64;
    float s = 0.f;
    #pragma unroll
    for (int c = 0; c < NCHUNK; ++c) s += dkp[((size_t)bh * NCHUNK + c) * HD + d];
    dkL[d] = fmaxf(s, EPSN);
  }
  __syncthreads();
  #pragma unroll
  for (int i = 0; i < 16; ++i) {
    const int idx = i * 256 + tid;
    const int d = idx >> 6;
    float s = 0.f;
    #pragma unroll
    for (int c = 0; c < NCHUNK; ++c)
      s += kvp[((size_t)bh * NCHUNK + c) * (HD * HD) + idx];
    kvs[(size_t)bh * (HD * HD) + idx] = s / (dqL[d] * dkL[d]);
  }
}

// ---------------------------------------------------------------------------
// W2T[b][c][h*64+d] = sum_e kvs[bh][d][e] * w_proj[c][h*64+e]
// ---------------------------------------------------------------------------
__global__ __launch_bounds__(256)
void w2_kernel(const float* __restrict__ kvs, const float* __restrict__ w_proj,
               float* __restrict__ W2T) {
  const int bh = blockIdx.x;
  const int b = bh / HEADS, h = bh % HEADS;
  const int c0 = blockIdx.y * 128;
  const int tid = threadIdx.x;
  const int tx = tid & 15, ty = tid >> 4;
  __shared__ float KVe[64][68];
  __shared__ float Wp[64][132];
  #pragma unroll
  for (int i = 0; i < 4; ++i) {
    const int idx = i * 256 + tid;
    const int d  = idx >> 4;
    const int e4 = (idx & 15) << 2;
    float4 v4 = *(const float4*)&kvs[(size_t)bh * (HD*HD) + (size_t)d * HD + e4];
    KVe[e4+0][d] = v4.x; KVe[e4+1][d] = v4.y;
    KVe[e4+2][d] = v4.z; KVe[e4+3][d] = v4.w;
  }
  {
    const int c = tid >> 1, half = tid & 1;
    #pragma unroll
    for (int j = 0; j < 8; ++j) {
      const int e = half * 32 + j * 4;
      float4 v4 = *(const float4*)&w_proj[(size_t)(c0 + c) * DIMC + h * HD + e];
      Wp[e+0][c] = v4.x; Wp[e+1][c] = v4.y; Wp[e+2][c] = v4.z; Wp[e+3][c] = v4.w;
    }
  }
  __syncthreads();
  float acc[4][8] = {};
  for (int e = 0; e < 64; ++e) {
    float4 a4 = *(const float4*)&KVe[e][ty << 2];
    float4 b0 = *(const float4*)&Wp[e][tx << 3];
    float4 b1 = *(const float4*)&Wp[e][(tx << 3) + 4];
    float ar[4] = {a4.x, a4.y, a4.z, a4.w};
    float br[8] = {b0.x,b0.y,b0.z,b0.w,b1.x,b1.y,b1.z,b1.w};
    #pragma unroll
    for (int i = 0; i < 4; ++i)
      #pragma unroll
      for (int j = 0; j < 8; ++j)
        acc[i][j] = fmaf(ar[i], br[j], acc[i][j]);
  }
  float* W2Tb = W2T + (size_t)b * DIMC * DIMC;
  #pragma unroll
  for (int j = 0; j < 8; ++j)
    *(float4*)&W2Tb[(size_t)(c0 + (tx << 3) + j) * DIMC + h * HD + (ty << 2)] =
        make_float4(acc[0][j], acc[1][j], acc[2][j], acc[3][j]);
}

// ---------------------------------------------------------------------------
// W3T[b][c][m] = sum_k W2T[b][c][k] * Wq^T[m][k]   (MFMA bf16x3)
// ---------------------------------------------------------------------------
__global__ __launch_bounds__(256)
void w3t_mfma(const u16* __restrict__ w2c, const u16* __restrict__ wqt,
              float* __restrict__ W3T) {
  const int tid = threadIdx.x;
  const int w = tid >> 6, l = tid & 63;
  const int lr16 = l & 15, cg = l >> 4;
  const int cx = blockIdx.x, my = blockIdx.y, b = blockIdx.z;

  const u16* wbase[3];
  #pragma unroll
  for (int ot = 0; ot < 3; ++ot)
    wbase[ot] = wqt + (size_t)(my * 12 + w * 3 + ot) * ROWTILE_U16 + (l << 3);
  const u16* abase[4];
  #pragma unroll
  for (int tt = 0; tt < 4; ++tt)
    abase[tt] = w2c + (size_t)(b * 48 + cx * 4 + tt) * ROWTILE_U16 + (l << 3);

  f32x4 acc[4][3];
  #pragma unroll
  for (int tt = 0; tt < 4; ++tt)
    #pragma unroll
    for (int ot = 0; ot < 3; ++ot)
      acc[tt][ot] = (f32x4){0.f, 0.f, 0.f, 0.f};

  for (int kt = 0; kt < KT; ++kt) {
    const int off = kt * TILE_U16;
    short8 bh_[3], bl_[3];
    #pragma unroll
    for (int ot = 0; ot < 3; ++ot) {
      bh_[ot] = *(const short8*)(wbase[ot] + off);
      bl_[ot] = *(const short8*)(wbase[ot] + off + 512);
    }
    #pragma unroll
    for (int tt = 0; tt < 4; ++tt) {
      short8 ah = *(const short8*)(abase[tt] + off);
      short8 al = *(const short8*)(abase[tt] + off + 512);
      #pragma unroll
      for (int ot = 0; ot < 3; ++ot) {
        acc[tt][ot] = __builtin_amdgcn_mfma_f32_16x16x32_bf16(ah, bh_[ot], acc[tt][ot], 0, 0, 0);
        acc[tt][ot] = __builtin_amdgcn_mfma_f32_16x16x32_bf16(ah, bl_[ot], acc[tt][ot], 0, 0, 0);
        acc[tt][ot] = __builtin_amdgcn_mfma_f32_16x16x32_bf16(al, bh_[ot], acc[tt][ot], 0, 0, 0);
      }
    }
  }
  float* Wb = W3T + (size_t)b * DIMC * DIMC;
  #pragma unroll
  for (int ot = 0; ot < 3; ++ot) {
    const int col = my * 192 + w * 48 + ot * 16 + lr16;
    #pragma unroll
    for (int tt = 0; tt < 4; ++tt) {
      const int row0 = cx * 64 + tt * 16 + cg * 4;
      #pragma unroll
      for (int r = 0; r < 4; ++r)
        Wb[(size_t)(row0 + r) * DIMC + col] = acc[tt][ot][r];
    }
  }
}

// ---------------------------------------------------------------------------
// out[b][n][c] = sum_m x[b][n][m] * W3T[b][c][m] + bias[c]
// A double-buffered through LDS + B register prefetch 1 kt ahead (same
// software pipeline as qkv_stage1).
// ---------------------------------------------------------------------------
__global__ __launch_bounds__(256, 3)
void final_gemm_mfma(const u16* __restrict__ xc, const u16* __restrict__ w3c,
                     const float* __restrict__ bias, float* __restrict__ out) {
  const int tid = threadIdx.x;
  const int w = tid >> 6, l = tid & 63;
  const int lr16 = l & 15, cg = l >> 4;
  const int ntile = blockIdx.x;
  const int c0 = blockIdx.y * 192;
  const int b = ntile >> 6;
  const int colbase0 = c0 + w * 48;

  __shared__ __align__(16) u16 alds[8192];   // 2 x 4096 u16

  const u16* wbase[3];
  #pragma unroll
  for (int ot = 0; ot < 3; ++ot) {
    const int c = colbase0 + ot * 16;
    wbase[ot] = w3c + (size_t)(b * (DIMC/16) + (c >> 4)) * ROWTILE_U16 + (l << 3);
  }
  const u16* gw0 = xc + (size_t)(ntile * 4 + w) * ROWTILE_U16 + (l << 3);

  // prologue: stage A kt=0 into buf0; preload B[0]
  {
    uint4 a0 = *(const uint4*)gw0;
    uint4 a1 = *(const uint4*)(gw0 + 512);
    *(uint4*)(alds + w * 1024 + (l << 3))       = a0;
    *(uint4*)(alds + w * 1024 + 512 + (l << 3)) = a1;
  }
  short8 bc_h[3], bc_l[3];
  #pragma unroll
  for (int ot = 0; ot < 3; ++ot) {
    bc_h[ot] = *(const short8*)(wbase[ot]);
    bc_l[ot] = *(const short8*)(wbase[ot] + 512);
  }
  __syncthreads();

  f32x4 acc[4][3];
  #pragma unroll
  for (int tt = 0; tt < 4; ++tt)
    #pragma unroll
    for (int ot = 0; ot < 3; ++ot)
      acc[tt][ot] = (f32x4){0.f, 0.f, 0.f, 0.f};

  #pragma unroll 2
  for (int kt = 0; kt < KT; ++kt) {
    const int cur = (kt & 1) << 12;
    const int nxt = cur ^ 4096;
    uint4 s0, s1;
    short8 bn_h[3], bn_l[3];
    if (kt + 1 < KT) {
      const u16* g = gw0 + (kt + 1) * TILE_U16;
      s0 = *(const uint4*)g;
      s1 = *(const uint4*)(g + 512);
      const int noff = (kt + 1) * TILE_U16;
      #pragma unroll
      for (int ot = 0; ot < 3; ++ot) {
        bn_h[ot] = *(const short8*)(wbase[ot] + noff);
        bn_l[ot] = *(const short8*)(wbase[ot] + noff + 512);
      }
    }
    #pragma unroll
    for (int tt = 0; tt < 4; ++tt) {
      short8 ah = *(const short8*)(alds + cur + tt * 1024 + (l << 3));
      short8 al = *(const short8*)(alds + cur + tt * 1024 + 512 + (l << 3));
      #pragma unroll
      for (int ot = 0; ot < 3; ++ot) {
        acc[tt][ot] = __builtin_amdgcn_mfma_f32_16x16x32_bf16(ah, bc_h[ot], acc[tt][ot], 0, 0, 0);
        acc[tt][ot] = __builtin_amdgcn_mfma_f32_16x16x32_bf16(ah, bc_l[ot], acc[tt][ot], 0, 0, 0);
        acc[tt][ot] = __builtin_amdgcn_mfma_f32_16x16x32_bf16(al, bc_h[ot], acc[tt][ot], 0, 0, 0);
      }
    }
    if (kt + 1 < KT) {
      *(uint4*)(alds + nxt + w * 1024 + (l << 3))       = s0;
      *(uint4*)(alds + nxt + w * 1024 + 512 + (l << 3)) = s1;
      #pragma unroll
      for (int ot = 0; ot < 3; ++ot) {
        bc_h[ot] = bn_h[ot];
        bc_l[ot] = bn_l[ot];
      }
    }
    __syncthreads();
  }
  #pragma unroll
  for (int ot = 0; ot < 3; ++ot) {
    const int col = colbase0 + ot * 16 + lr16;
    const float bv = bias[col];
    #pragma unroll
    for (int tt = 0; tt < 4; ++tt) {
      const size_t row0 = (size_t)ntile * 64 + tt * 16 + cg * 4;
      #pragma unroll
      for (int r = 0; r < 4; ++r)
        out[(row0 + r) * DIMC + col] = acc[tt][ot][r] + bv;
    }
  }
}

// ---------------------------------------------------------------------------
extern "C" void kernel_launch(void* const* d_in, const int* in_sizes, int n_in,
                              void* d_out, int out_size, void* d_ws, size_t ws_size,
                              hipStream_t stream) {
  const float* x      = (const float*)d_in[0];
  const float* w_qkv  = (const float*)d_in[1];
  const float* w_proj = (const float*)d_in[2];
  const float* b_proj = (const float*)d_in[3];
  float* out = (float*)d_out;
  float* ws  = (float*)d_ws;

  // workspace layout (WBUF holds W2T first, then is reused for W3T)
  const size_t KVP_SZ = (size_t)BHN * NCHUNK * HD * HD;
  const size_t DQP_SZ = (size_t)BHN * NCHUNK * HD;
  const size_t KVS_SZ = (size_t)BHN * HD * HD;
  const size_t W_SZ   = (size_t)BATCH * DIMC * DIMC;
  const size_t XC_U16  = (size_t)(MTOK/16) * ROWTILE_U16;
  const size_t WC_U16  = (size_t)(THREEC/16) * ROWTILE_U16;
  const size_t WQT_U16 = (size_t)(DIMC/16) * ROWTILE_U16;
  const size_t W2C_U16 = (size_t)(BATCH*DIMC/16) * ROWTILE_U16;
  const size_t W3C_U16 = (size_t)(BATCH*DIMC/16) * ROWTILE_U16;
  float* kvp  = ws;
  float* dqp  = kvp + KVP_SZ;
  float* dkp  = dqp + DQP_SZ;
  float* kvs  = dkp + DQP_SZ;
  float* WBUF = kvs + KVS_SZ;
  u16*   xc   = (u16*)(WBUF + W_SZ);
  u16*   wc   = xc + XC_U16;
  u16*   wqt  = wc + WC_U16;
  u16*   w2c  = wqt + WQT_U16;
  u16*   w3c  = w2c + W2C_U16;
  const size_t need_bytes =
      (KVP_SZ + 2*DQP_SZ + KVS_SZ + W_SZ) * sizeof(float) +
      (XC_U16 + WC_U16 + WQT_U16 + W2C_U16 + W3C_U16) * sizeof(u16);
  if (ws_size < need_bytes) return;   // clean validation failure, not a fault

  const dim3 blk(256);
  // 0) split x, w_qkv, w_qkv_q^T into fragment tiles
  split_tiles<<<dim3((MTOK/16) * KT / 4), blk, 0, stream>>>(x, xc, MTOK/16);
  split_tiles<<<dim3((THREEC/16) * KT / 4), blk, 0, stream>>>(w_qkv, wc, THREEC/16);
  split_tiles_t<<<dim3((DIMC/16) * KT / 4), blk, 0, stream>>>(w_qkv, wqt, DIMC/16, DIMC);
  // 1) fused qkv GEMM + |q|,|k| sums + MFMA kv outer product
  qkv_stage1<<<dim3(BHN * NCHUNK), blk, 0, stream>>>(xc, wc, kvp, dqp, dkp);
  // 2) reduce partials + fold denominators
  kv_reduce<<<dim3(BHN), blk, 0, stream>>>(kvp, dqp, dkp, kvs);
  // 3) W2T (transposed store)
  w2_kernel<<<dim3(BHN, DIMC/128), blk, 0, stream>>>(kvs, w_proj, WBUF);
  // 4) split W2T -> w2c
  split_tiles<<<dim3((BATCH*DIMC/16) * KT / 4), blk, 0, stream>>>(WBUF, w2c, BATCH*DIMC/16);
  // 5) W3T = W2T x Wq^T (MFMA bf16x3), overwrites WBUF
  w3t_mfma<<<dim3(DIMC/64, DIMC/192, BATCH), blk, 0, stream>>>(w2c, wqt, WBUF);
  // 6) split W3T -> w3c
  split_tiles<<<dim3((BATCH*DIMC/16) * KT / 4), blk, 0, stream>>>(WBUF, w3c, BATCH*DIMC/16);
  // 7) out = x @ W3^T + bias
  final_gemm_mfma<<<dim3(MTOK/64, DIMC/192), blk, 0, stream>>>(xc, w3c, b_proj, out);
}

// Round 18
// 523.064 us; speedup vs baseline: 1.0165x; 1.0165x over previous
//
#include <hip/hip_runtime.h>
#include <cstddef>
#include <cstdint>

#define DIMC   768
#define HEADS  12
#define HD     64
#define BATCH  8
#define SEQ    4096
#define MTOK   (BATCH*SEQ)     // 32768
#define THREEC (3*DIMC)        // 2304
#define BHN    (BATCH*HEADS)   // 96
#define NCHUNK 8               // token chunks per (b,h)
#define CHTOK  (SEQ/NCHUNK)    // 512 tokens per chunk
#define EPSN   1e-12f
#define KT     (DIMC/32)       // 24 k-tiles
#define TILE_U16 1024          // one (16-row x 32-k) tile: hi 512 + lo 512 u16
#define ROWTILE_U16 (KT*TILE_U16)  // 24576 u16 per 16-row block

typedef unsigned short u16;
typedef unsigned int   u32;
typedef __attribute__((ext_vector_type(8))) short short8;   // 8 bf16 (4 VGPR)
typedef __attribute__((ext_vector_type(4))) float f32x4;

__device__ inline u16 bf16_rne(float f) {
  u32 u = __float_as_uint(f);
  u32 r = u + 0x7fffu + ((u >> 16) & 1u);
  return (u16)(r >> 16);
}

// packed f32x2 -> bf16x2 (low16 = cvt(a), high16 = cvt(b)); gfx950 HW RNE
__device__ inline u32 cvt_pk_bf16(float a, float b) {
  u32 r;
  asm("v_cvt_pk_bf16_f32 %0, %1, %2" : "=v"(r) : "v"(a), "v"(b));
  return r;
}

// ---------------------------------------------------------------------------
// Split fp32 [R][768] row-major -> bf16 hi/lo in MFMA-FRAGMENT-TILE order.
// ---------------------------------------------------------------------------
__global__ __launch_bounds__(256)
void split_tiles(const float* __restrict__ in, u16* __restrict__ outp,
                 int nrowtiles) {
  const int l = threadIdx.x & 63;
  const int ntiles = nrowtiles * KT;
  for (int gw = (blockIdx.x * 256 + threadIdx.x) >> 6; gw < ntiles;
       gw += (gridDim.x * 256) >> 6) {
    const int rt = gw / KT, kt = gw % KT;
    const float* src = in + (size_t)(rt * 16 + (l & 15)) * DIMC + kt * 32 + (l >> 4) * 8;
    float4 x0 = *(const float4*)src;
    float4 x1 = *(const float4*)(src + 4);
    float xs[8] = {x0.x, x0.y, x0.z, x0.w, x1.x, x1.y, x1.z, x1.w};
    u32 hw[4], lw[4];
    #pragma unroll
    for (int i = 0; i < 4; ++i) {
      u16 h0 = bf16_rne(xs[2*i]);
      u16 h1 = bf16_rne(xs[2*i+1]);
      float r0 = xs[2*i]   - __uint_as_float(((u32)h0) << 16);
      float r1 = xs[2*i+1] - __uint_as_float(((u32)h1) << 16);
      u16 l0 = bf16_rne(r0);
      u16 l1 = bf16_rne(r1);
      hw[i] = (u32)h0 | ((u32)h1 << 16);
      lw[i] = (u32)l0 | ((u32)l1 << 16);
    }
    u16* tb = outp + (size_t)gw * TILE_U16;
    *(uint4*)(tb + l * 8)       = make_uint4(hw[0], hw[1], hw[2], hw[3]);
    *(uint4*)(tb + 512 + l * 8) = make_uint4(lw[0], lw[1], lw[2], lw[3]);
  }
}

// ---------------------------------------------------------------------------
// Transposed split: source element (row rr, k kk) = in[kk*ld + rr].
// ---------------------------------------------------------------------------
__global__ __launch_bounds__(256)
void split_tiles_t(const float* __restrict__ in, u16* __restrict__ outp,
                   int nrowtiles, int ld) {
  const int l = threadIdx.x & 63;
  const int ntiles = nrowtiles * KT;
  for (int gw = (blockIdx.x * 256 + threadIdx.x) >> 6; gw < ntiles;
       gw += (gridDim.x * 256) >> 6) {
    const int rt = gw / KT, kt = gw % KT;
    const int m = rt * 16 + (l & 15);
    const int k0 = kt * 32 + (l >> 4) * 8;
    float xs[8];
    #pragma unroll
    for (int j = 0; j < 8; ++j) xs[j] = in[(size_t)(k0 + j) * ld + m];
    u32 hw[4], lw[4];
    #pragma unroll
    for (int i = 0; i < 4; ++i) {
      u16 h0 = bf16_rne(xs[2*i]);
      u16 h1 = bf16_rne(xs[2*i+1]);
      float r0 = xs[2*i]   - __uint_as_float(((u32)h0) << 16);
      float r1 = xs[2*i+1] - __uint_as_float(((u32)h1) << 16);
      u16 l0 = bf16_rne(r0);
      u16 l1 = bf16_rne(r1);
      hw[i] = (u32)h0 | ((u32)h1 << 16);
      lw[i] = (u32)l0 | ((u32)l1 << 16);
    }
    u16* tb = outp + (size_t)gw * TILE_U16;
    *(uint4*)(tb + l * 8)       = make_uint4(hw[0], hw[1], hw[2], hw[3]);
    *(uint4*)(tb + 512 + l * 8) = make_uint4(lw[0], lw[1], lw[2], lw[3]);
  }
}

// ---------------------------------------------------------------------------
// Stage 1: qkv GEMM (MFMA bf16x3) + |q|,|k| sums + MFMA kv outer product.
// R15 structure (best measured): A double-buffered through LDS, B loaded
// per-kt. setprio(1) wraps the MFMA clusters: with 3 independent blocks/CU
// at different phases, MFMA-phase waves get scheduler priority over waves
// in scatter/staging phases (T5 regime: wave role diversity).
// ---------------------------------------------------------------------------
__global__ __launch_bounds__(256, 3)
void qkv_stage1(const u16* __restrict__ xc, const u16* __restrict__ wc,
                float* __restrict__ kvp, float* __restrict__ dqp,
                float* __restrict__ dkp) {
  const int bid = blockIdx.x;
  const int h = bid % HEADS;
  const int bc = bid / HEADS;
  const int b = bc >> 3, chunk = bc & 7;
  const int bh = b * HEADS + h;
  const int si = bh * NCHUNK + chunk;

  const int tid = threadIdx.x;
  const int w = tid >> 6, l = tid & 63;
  const int lr16 = l & 15, cg = l >> 4;

  __shared__ __align__(16) unsigned char smem[33792];
  u16* lds16 = (u16*)smem;   // kt loop: A-dbuf 2x4096 u16 at [0,8192)
                             // scatter: k^T tiles [0,8192), v tiles [8192,16384)
  float* red = (float*)smem; // epilogue scratch

  f32x4 kvacc[4] = {(f32x4){0,0,0,0},(f32x4){0,0,0,0},(f32x4){0,0,0,0},(f32x4){0,0,0,0}};
  float dsum_q = 0.f, dsum_k = 0.f;

  // B-frag bases: section ot (q/k/v), rows ot*DIMC + h*64 + w*16 .. +16
  const u16* wbase[3];
  #pragma unroll
  for (int ot = 0; ot < 3; ++ot) {
    const int grow = ot * DIMC + h * HD + w * 16;
    wbase[ot] = wc + (size_t)(grow >> 4) * ROWTILE_U16 + (l << 3);
  }
  const int atile0 = (b * SEQ + chunk * CHTOK) >> 4;

  for (int sub = 0; sub < 8; ++sub) {
    const u16* asub = xc + (size_t)(atile0 + sub * 4) * ROWTILE_U16;
    const u16* gw0 = asub + (size_t)w * ROWTILE_U16 + (l << 3);
    __syncthreads();   // prev sub's kv-MFMA reads done -> LDS reusable
    // prologue: wave w stages its tile (hi+lo pieces) for kt=0 into buf0
    {
      uint4 s0 = *(const uint4*)gw0;
      uint4 s1 = *(const uint4*)(gw0 + 512);
      *(uint4*)(lds16 + w * 1024 + (l << 3))       = s0;
      *(uint4*)(lds16 + w * 1024 + 512 + (l << 3)) = s1;
    }
    __syncthreads();

    f32x4 acc[4][3];
    #pragma unroll
    for (int tt = 0; tt < 4; ++tt)
      #pragma unroll
      for (int ot = 0; ot < 3; ++ot)
        acc[tt][ot] = (f32x4){0.f, 0.f, 0.f, 0.f};

    for (int kt = 0; kt < KT; ++kt) {
      const int cur = (kt & 1) << 12;          // 0 or 4096 u16
      const int nxt = cur ^ 4096;
      // issue next-kt stage loads EARLY (latency hides under MFMAs)
      uint4 s0, s1;
      if (kt + 1 < KT) {
        const u16* g = gw0 + (kt + 1) * TILE_U16;
        s0 = *(const uint4*)g;
        s1 = *(const uint4*)(g + 512);
      }
      const int off = kt * TILE_U16;
      short8 bh_[3], bl_[3];
      #pragma unroll
      for (int ot = 0; ot < 3; ++ot) {
        bh_[ot] = *(const short8*)(wbase[ot] + off);
        bl_[ot] = *(const short8*)(wbase[ot] + off + 512);
      }
      __builtin_amdgcn_s_setprio(1);
      #pragma unroll
      for (int tt = 0; tt < 4; ++tt) {
        short8 ah = *(const short8*)(lds16 + cur + tt * 1024 + (l << 3));
        short8 al = *(const short8*)(lds16 + cur + tt * 1024 + 512 + (l << 3));
        #pragma unroll
        for (int ot = 0; ot < 3; ++ot) {
          acc[tt][ot] = __builtin_amdgcn_mfma_f32_16x16x32_bf16(ah, bh_[ot], acc[tt][ot], 0, 0, 0);
          acc[tt][ot] = __builtin_amdgcn_mfma_f32_16x16x32_bf16(ah, bl_[ot], acc[tt][ot], 0, 0, 0);
          acc[tt][ot] = __builtin_amdgcn_mfma_f32_16x16x32_bf16(al, bh_[ot], acc[tt][ot], 0, 0, 0);
        }
      }
      __builtin_amdgcn_s_setprio(0);
      if (kt + 1 < KT) {
        *(uint4*)(lds16 + nxt + w * 1024 + (l << 3))       = s0;
        *(uint4*)(lds16 + nxt + w * 1024 + 512 + (l << 3)) = s1;
      }
      __syncthreads();
    }
    // --- scatter phase (kt loop's trailing barrier protects A-dbuf readers)
    #pragma unroll
    for (int tt = 0; tt < 4; ++tt) {
      dsum_q += fabsf(acc[tt][0][0]);
      dsum_q += fabsf(acc[tt][0][1]);
      dsum_q += fabsf(acc[tt][0][2]);
      dsum_q += fabsf(acc[tt][0][3]);
    }
    #pragma unroll
    for (int sec = 1; sec < 3; ++sec) {
      const int region = (sec == 1) ? 0 : 8192;
      #pragma unroll
      for (int tt = 0; tt < 4; ++tt) {
        const float v0 = acc[tt][sec][0], v1 = acc[tt][sec][1];
        const float v2 = acc[tt][sec][2], v3 = acc[tt][sec][3];
        if (sec == 1) {
          dsum_k += fabsf(v0);
          dsum_k += fabsf(v1);
          dsum_k += fabsf(v2);
          dsum_k += fabsf(v3);
        }
        const u32 ph01 = cvt_pk_bf16(v0, v1);
        const u32 ph23 = cvt_pk_bf16(v2, v3);
        const float r0 = v0 - __uint_as_float(ph01 << 16);
        const float r1 = v1 - __uint_as_float(ph01 & 0xffff0000u);
        const float r2 = v2 - __uint_as_float(ph23 << 16);
        const float r3 = v3 - __uint_as_float(ph23 & 0xffff0000u);
        const u32 pl01 = cvt_pk_bf16(r0, r1);
        const u32 pl23 = cvt_pk_bf16(r2, r3);
        const int pos = region + (w * 2 + (tt >> 1)) * TILE_U16 +
                        ((lr16 | (((tt * 2 + (cg >> 1)) & 3) << 4)) << 3) +
                        ((cg & 1) << 2);
        *(uint2*)(lds16 + pos)       = make_uint2(ph01, ph23);
        *(uint2*)(lds16 + pos + 512) = make_uint2(pl01, pl23);
      }
    }
    __syncthreads();
    // kv MFMA: wave w owns d-tile w (rows w*16..+16), all 4 e-tiles, K=64
    {
      const u16* At = lds16 + w * 2 * TILE_U16;
      const u16* Bt = lds16 + 8192;
      __builtin_amdgcn_s_setprio(1);
      #pragma unroll
      for (int t2 = 0; t2 < 2; ++t2) {
        short8 kah = *(const short8*)(At + t2 * TILE_U16 + (l << 3));
        short8 kal = *(const short8*)(At + t2 * TILE_U16 + 512 + (l << 3));
        #pragma unroll
        for (int et = 0; et < 4; ++et) {
          short8 vbh = *(const short8*)(Bt + (et * 2 + t2) * TILE_U16 + (l << 3));
          short8 vbl = *(const short8*)(Bt + (et * 2 + t2) * TILE_U16 + 512 + (l << 3));
          kvacc[et] = __builtin_amdgcn_mfma_f32_16x16x32_bf16(kah, vbh, kvacc[et], 0, 0, 0);
          kvacc[et] = __builtin_amdgcn_mfma_f32_16x16x32_bf16(kah, vbl, kvacc[et], 0, 0, 0);
          kvacc[et] = __builtin_amdgcn_mfma_f32_16x16x32_bf16(kal, vbh, kvacc[et], 0, 0, 0);
        }
      }
      __builtin_amdgcn_s_setprio(0);
    }
  }
  // write kv partial: d = w*16 + cg*4 + r, e = et*16 + lr16
  float* ob = kvp + (size_t)si * (HD * HD);
  #pragma unroll
  for (int et = 0; et < 4; ++et)
    #pragma unroll
    for (int r = 0; r < 4; ++r)
      ob[(w * 16 + cg * 4 + r) * HD + et * 16 + lr16] = kvacc[et][r];
  // dq/dk reduction: red_q[64][4] @0, red_k[64][4] @256 (one writer per slot)
  __syncthreads();
  red[(w * 16 + lr16) * 4 + cg]       = dsum_q;
  red[256 + (w * 16 + lr16) * 4 + cg] = dsum_k;
  __syncthreads();
  if (tid < 64) {
    dqp[(size_t)si * HD + tid] = red[tid*4] + red[tid*4+1] + red[tid*4+2] + red[tid*4+3];
  } else if (tid < 128) {
    const int d = tid - 64;
    dkp[(size_t)si * HD + d] = red[256 + d*4] + red[256 + d*4+1] + red[256 + d*4+2] + red[256 + d*4+3];
  }
}

// ---------------------------------------------------------------------------
__global__ __launch_bounds__(256)
void kv_reduce(const float* __restrict__ kvp, const float* __restrict__ dqp,
               const float* __restrict__ dkp, float* __restrict__ kvs) {
  const int bh = blockIdx.x;
  const int tid = threadIdx.x;
  __shared__ float dqL[64], dkL[64];
  if (tid < 64) {
    float s = 0.f;
    #pragma unroll
    for (int c = 0; c < NCHUNK; ++c) s += dqp[((size_t)bh * NCHUNK + c) * HD + tid];
    dqL[tid] = fmaxf(s, EPSN);
  } else if (tid < 128) {
    const int d = tid - 64;
    float s = 0.f;
    #pragma unroll
    for (int c = 0; c < NCHUNK; ++c) s += dkp[((size_t)bh * NCHUNK + c) * HD + d];
    dkL[d] = fmaxf(s, EPSN);
  }
  __syncthreads();
  #pragma unroll
  for (int i = 0; i < 16; ++i) {
    const int idx = i * 256 + tid;
    const int d = idx >> 6;
    float s = 0.f;
    #pragma unroll
    for (int c = 0; c < NCHUNK; ++c)
      s += kvp[((size_t)bh * NCHUNK + c) * (HD * HD) + idx];
    kvs[(size_t)bh * (HD * HD) + idx] = s / (dqL[d] * dkL[d]);
  }
}

// ---------------------------------------------------------------------------
// W2T[b][c][h*64+d] = sum_e kvs[bh][d][e] * w_proj[c][h*64+e]
// ---------------------------------------------------------------------------
__global__ __launch_bounds__(256)
void w2_kernel(const float* __restrict__ kvs, const float* __restrict__ w_proj,
               float* __restrict__ W2T) {
  const int bh = blockIdx.x;
  const int b = bh / HEADS, h = bh % HEADS;
  const int c0 = blockIdx.y * 128;
  const int tid = threadIdx.x;
  const int tx = tid & 15, ty = tid >> 4;
  __shared__ float KVe[64][68];
  __shared__ float Wp[64][132];
  #pragma unroll
  for (int i = 0; i < 4; ++i) {
    const int idx = i * 256 + tid;
    const int d  = idx >> 4;
    const int e4 = (idx & 15) << 2;
    float4 v4 = *(const float4*)&kvs[(size_t)bh * (HD*HD) + (size_t)d * HD + e4];
    KVe[e4+0][d] = v4.x; KVe[e4+1][d] = v4.y;
    KVe[e4+2][d] = v4.z; KVe[e4+3][d] = v4.w;
  }
  {
    const int c = tid >> 1, half = tid & 1;
    #pragma unroll
    for (int j = 0; j < 8; ++j) {
      const int e = half * 32 + j * 4;
      float4 v4 = *(const float4*)&w_proj[(size_t)(c0 + c) * DIMC + h * HD + e];
      Wp[e+0][c] = v4.x; Wp[e+1][c] = v4.y; Wp[e+2][c] = v4.z; Wp[e+3][c] = v4.w;
    }
  }
  __syncthreads();
  float acc[4][8] = {};
  for (int e = 0; e < 64; ++e) {
    float4 a4 = *(const float4*)&KVe[e][ty << 2];
    float4 b0 = *(const float4*)&Wp[e][tx << 3];
    float4 b1 = *(const float4*)&Wp[e][(tx << 3) + 4];
    float ar[4] = {a4.x, a4.y, a4.z, a4.w};
    float br[8] = {b0.x,b0.y,b0.z,b0.w,b1.x,b1.y,b1.z,b1.w};
    #pragma unroll
    for (int i = 0; i < 4; ++i)
      #pragma unroll
      for (int j = 0; j < 8; ++j)
        acc[i][j] = fmaf(ar[i], br[j], acc[i][j]);
  }
  float* W2Tb = W2T + (size_t)b * DIMC * DIMC;
  #pragma unroll
  for (int j = 0; j < 8; ++j)
    *(float4*)&W2Tb[(size_t)(c0 + (tx << 3) + j) * DIMC + h * HD + (ty << 2)] =
        make_float4(acc[0][j], acc[1][j], acc[2][j], acc[3][j]);
}

// ---------------------------------------------------------------------------
// W3T[b][c][m] = sum_k W2T[b][c][k] * Wq^T[m][k]   (MFMA bf16x3)
// ---------------------------------------------------------------------------
__global__ __launch_bounds__(256)
void w3t_mfma(const u16* __restrict__ w2c, const u16* __restrict__ wqt,
              float* __restrict__ W3T) {
  const int tid = threadIdx.x;
  const int w = tid >> 6, l = tid & 63;
  const int lr16 = l & 15, cg = l >> 4;
  const int cx = blockIdx.x, my = blockIdx.y, b = blockIdx.z;

  const u16* wbase[3];
  #pragma unroll
  for (int ot = 0; ot < 3; ++ot)
    wbase[ot] = wqt + (size_t)(my * 12 + w * 3 + ot) * ROWTILE_U16 + (l << 3);
  const u16* abase[4];
  #pragma unroll
  for (int tt = 0; tt < 4; ++tt)
    abase[tt] = w2c + (size_t)(b * 48 + cx * 4 + tt) * ROWTILE_U16 + (l << 3);

  f32x4 acc[4][3];
  #pragma unroll
  for (int tt = 0; tt < 4; ++tt)
    #pragma unroll
    for (int ot = 0; ot < 3; ++ot)
      acc[tt][ot] = (f32x4){0.f, 0.f, 0.f, 0.f};

  for (int kt = 0; kt < KT; ++kt) {
    const int off = kt * TILE_U16;
    short8 bh_[3], bl_[3];
    #pragma unroll
    for (int ot = 0; ot < 3; ++ot) {
      bh_[ot] = *(const short8*)(wbase[ot] + off);
      bl_[ot] = *(const short8*)(wbase[ot] + off + 512);
    }
    #pragma unroll
    for (int tt = 0; tt < 4; ++tt) {
      short8 ah = *(const short8*)(abase[tt] + off);
      short8 al = *(const short8*)(abase[tt] + off + 512);
      #pragma unroll
      for (int ot = 0; ot < 3; ++ot) {
        acc[tt][ot] = __builtin_amdgcn_mfma_f32_16x16x32_bf16(ah, bh_[ot], acc[tt][ot], 0, 0, 0);
        acc[tt][ot] = __builtin_amdgcn_mfma_f32_16x16x32_bf16(ah, bl_[ot], acc[tt][ot], 0, 0, 0);
        acc[tt][ot] = __builtin_amdgcn_mfma_f32_16x16x32_bf16(al, bh_[ot], acc[tt][ot], 0, 0, 0);
      }
    }
  }
  float* Wb = W3T + (size_t)b * DIMC * DIMC;
  #pragma unroll
  for (int ot = 0; ot < 3; ++ot) {
    const int col = my * 192 + w * 48 + ot * 16 + lr16;
    #pragma unroll
    for (int tt = 0; tt < 4; ++tt) {
      const int row0 = cx * 64 + tt * 16 + cg * 4;
      #pragma unroll
      for (int r = 0; r < 4; ++r)
        Wb[(size_t)(row0 + r) * DIMC + col] = acc[tt][ot][r];
    }
  }
}

// ---------------------------------------------------------------------------
// out[b][n][c] = sum_m x[b][n][m] * W3T[b][c][m] + bias[c]
// R16 structure (best measured): A double-buffered through LDS, B per-kt.
// setprio around the MFMA cluster (T5).
// ---------------------------------------------------------------------------
__global__ __launch_bounds__(256, 3)
void final_gemm_mfma(const u16* __restrict__ xc, const u16* __restrict__ w3c,
                     const float* __restrict__ bias, float* __restrict__ out) {
  const int tid = threadIdx.x;
  const int w = tid >> 6, l = tid & 63;
  const int lr16 = l & 15, cg = l >> 4;
  const int ntile = blockIdx.x;
  const int c0 = blockIdx.y * 192;
  const int b = ntile >> 6;
  const int colbase0 = c0 + w * 48;

  __shared__ __align__(16) u16 alds[8192];   // 2 x 4096 u16

  const u16* wbase[3];
  #pragma unroll
  for (int ot = 0; ot < 3; ++ot) {
    const int c = colbase0 + ot * 16;
    wbase[ot] = w3c + (size_t)(b * (DIMC/16) + (c >> 4)) * ROWTILE_U16 + (l << 3);
  }
  const u16* gw0 = xc + (size_t)(ntile * 4 + w) * ROWTILE_U16 + (l << 3);

  // prologue: stage kt=0 into buf0
  {
    uint4 a0 = *(const uint4*)gw0;
    uint4 a1 = *(const uint4*)(gw0 + 512);
    *(uint4*)(alds + w * 1024 + (l << 3))       = a0;
    *(uint4*)(alds + w * 1024 + 512 + (l << 3)) = a1;
  }
  __syncthreads();

  f32x4 acc[4][3];
  #pragma unroll
  for (int tt = 0; tt < 4; ++tt)
    #pragma unroll
    for (int ot = 0; ot < 3; ++ot)
      acc[tt][ot] = (f32x4){0.f, 0.f, 0.f, 0.f};

  for (int kt = 0; kt < KT; ++kt) {
    const int cur = (kt & 1) << 12;
    const int nxt = cur ^ 4096;
    uint4 s0, s1;
    if (kt + 1 < KT) {
      const u16* g = gw0 + (kt + 1) * TILE_U16;
      s0 = *(const uint4*)g;
      s1 = *(const uint4*)(g + 512);
    }
    const int off = kt * TILE_U16;
    short8 bh_[3], bl_[3];
    #pragma unroll
    for (int ot = 0; ot < 3; ++ot) {
      bh_[ot] = *(const short8*)(wbase[ot] + off);
      bl_[ot] = *(const short8*)(wbase[ot] + off + 512);
    }
    __builtin_amdgcn_s_setprio(1);
    #pragma unroll
    for (int tt = 0; tt < 4; ++tt) {
      short8 ah = *(const short8*)(alds + cur + tt * 1024 + (l << 3));
      short8 al = *(const short8*)(alds + cur + tt * 1024 + 512 + (l << 3));
      #pragma unroll
      for (int ot = 0; ot < 3; ++ot) {
        acc[tt][ot] = __builtin_amdgcn_mfma_f32_16x16x32_bf16(ah, bh_[ot], acc[tt][ot], 0, 0, 0);
        acc[tt][ot] = __builtin_amdgcn_mfma_f32_16x16x32_bf16(ah, bl_[ot], acc[tt][ot], 0, 0, 0);
        acc[tt][ot] = __builtin_amdgcn_mfma_f32_16x16x32_bf16(al, bh_[ot], acc[tt][ot], 0, 0, 0);
      }
    }
    __builtin_amdgcn_s_setprio(0);
    if (kt + 1 < KT) {
      *(uint4*)(alds + nxt + w * 1024 + (l << 3))       = s0;
      *(uint4*)(alds + nxt + w * 1024 + 512 + (l << 3)) = s1;
    }
    __syncthreads();
  }
  #pragma unroll
  for (int ot = 0; ot < 3; ++ot) {
    const int col = colbase0 + ot * 16 + lr16;
    const float bv = bias[col];
    #pragma unroll
    for (int tt = 0; tt < 4; ++tt) {
      const size_t row0 = (size_t)ntile * 64 + tt * 16 + cg * 4;
      #pragma unroll
      for (int r = 0; r < 4; ++r)
        out[(row0 + r) * DIMC + col] = acc[tt][ot][r] + bv;
    }
  }
}

// ---------------------------------------------------------------------------
extern "C" void kernel_launch(void* const* d_in, const int* in_sizes, int n_in,
                              void* d_out, int out_size, void* d_ws, size_t ws_size,
                              hipStream_t stream) {
  const float* x      = (const float*)d_in[0];
  const float* w_qkv  = (const float*)d_in[1];
  const float* w_proj = (const float*)d_in[2];
  const float* b_proj = (const float*)d_in[3];
  float* out = (float*)d_out;
  float* ws  = (float*)d_ws;

  // workspace layout (WBUF holds W2T first, then is reused for W3T)
  const size_t KVP_SZ = (size_t)BHN * NCHUNK * HD * HD;
  const size_t DQP_SZ = (size_t)BHN * NCHUNK * HD;
  const size_t KVS_SZ = (size_t)BHN * HD * HD;
  const size_t W_SZ   = (size_t)BATCH * DIMC * DIMC;
  const size_t XC_U16  = (size_t)(MTOK/16) * ROWTILE_U16;
  const size_t WC_U16  = (size_t)(THREEC/16) * ROWTILE_U16;
  const size_t WQT_U16 = (size_t)(DIMC/16) * ROWTILE_U16;
  const size_t W2C_U16 = (size_t)(BATCH*DIMC/16) * ROWTILE_U16;
  const size_t W3C_U16 = (size_t)(BATCH*DIMC/16) * ROWTILE_U16;
  float* kvp  = ws;
  float* dqp  = kvp + KVP_SZ;
  float* dkp  = dqp + DQP_SZ;
  float* kvs  = dkp + DQP_SZ;
  float* WBUF = kvs + KVS_SZ;
  u16*   xc   = (u16*)(WBUF + W_SZ);
  u16*   wc   = xc + XC_U16;
  u16*   wqt  = wc + WC_U16;
  u16*   w2c  = wqt + WQT_U16;
  u16*   w3c  = w2c + W2C_U16;
  const size_t need_bytes =
      (KVP_SZ + 2*DQP_SZ + KVS_SZ + W_SZ) * sizeof(float) +
      (XC_U16 + WC_U16 + WQT_U16 + W2C_U16 + W3C_U16) * sizeof(u16);
  if (ws_size < need_bytes) return;   // clean validation failure, not a fault

  const dim3 blk(256);
  // 0) split x, w_qkv, w_qkv_q^T into fragment tiles
  split_tiles<<<dim3((MTOK/16) * KT / 4), blk, 0, stream>>>(x, xc, MTOK/16);
  split_tiles<<<dim3((THREEC/16) * KT / 4), blk, 0, stream>>>(w_qkv, wc, THREEC/16);
  split_tiles_t<<<dim3((DIMC/16) * KT / 4), blk, 0, stream>>>(w_qkv, wqt, DIMC/16, DIMC);
  // 1) fused qkv GEMM + |q|,|k| sums + MFMA kv outer product
  qkv_stage1<<<dim3(BHN * NCHUNK), blk, 0, stream>>>(xc, wc, kvp, dqp, dkp);
  // 2) reduce partials + fold denominators
  kv_reduce<<<dim3(BHN), blk, 0, stream>>>(kvp, dqp, dkp, kvs);
  // 3) W2T (transposed store)
  w2_kernel<<<dim3(BHN, DIMC/128), blk, 0, stream>>>(kvs, w_proj, WBUF);
  // 4) split W2T -> w2c
  split_tiles<<<dim3((BATCH*DIMC/16) * KT / 4), blk, 0, stream>>>(WBUF, w2c, BATCH*DIMC/16);
  // 5) W3T = W2T x Wq^T (MFMA bf16x3), overwrites WBUF
  w3t_mfma<<<dim3(DIMC/64, DIMC/192, BATCH), blk, 0, stream>>>(w2c, wqt, WBUF);
  // 6) split W3T -> w3c
  split_tiles<<<dim3((BATCH*DIMC/16) * KT / 4), blk, 0, stream>>>(WBUF, w3c, BATCH*DIMC/16);
  // 7) out = x @ W3^T + bias
  final_gemm_mfma<<<dim3(MTOK/64, DIMC/192), blk, 0, stream>>>(xc, w3c, b_proj, out);
}

// Round 19
// 504.375 us; speedup vs baseline: 1.0542x; 1.0371x over previous
//
#include <hip/hip_runtime.h>
#include <cstddef>
#include <cstdint>

#define DIMC   768
#define HEADS  12
#define HD     64
#define BATCH  8
#define SEQ    4096
#define MTOK   (BATCH*SEQ)     // 32768
#define THREEC (3*DIMC)        // 2304
#define BHN    (BATCH*HEADS)   // 96
#define NCHUNK 8               // token chunks per (b,h)
#define CHTOK  (SEQ/NCHUNK)    // 512 tokens per chunk
#define EPSN   1e-12f
#define KT     (DIMC/32)       // 24 k-tiles
#define TILE_U16 1024          // one (16-row x 32-k) tile: hi 512 + lo 512 u16
#define ROWTILE_U16 (KT*TILE_U16)  // 24576 u16 per 16-row block

typedef unsigned short u16;
typedef unsigned int   u32;
typedef __attribute__((ext_vector_type(8))) short short8;   // 8 bf16 (4 VGPR)
typedef __attribute__((ext_vector_type(4))) float f32x4;

__device__ inline u16 bf16_rne(float f) {
  u32 u = __float_as_uint(f);
  u32 r = u + 0x7fffu + ((u >> 16) & 1u);
  return (u16)(r >> 16);
}

// packed f32x2 -> bf16x2 (low16 = cvt(a), high16 = cvt(b)); gfx950 HW RNE
__device__ inline u32 cvt_pk_bf16(float a, float b) {
  u32 r;
  asm("v_cvt_pk_bf16_f32 %0, %1, %2" : "=v"(r) : "v"(a), "v"(b));
  return r;
}

// ---------------------------------------------------------------------------
// Split fp32 [R][768] row-major -> bf16 hi/lo in MFMA-FRAGMENT-TILE order.
// ---------------------------------------------------------------------------
__global__ __launch_bounds__(256)
void split_tiles(const float* __restrict__ in, u16* __restrict__ outp,
                 int nrowtiles) {
  const int l = threadIdx.x & 63;
  const int ntiles = nrowtiles * KT;
  for (int gw = (blockIdx.x * 256 + threadIdx.x) >> 6; gw < ntiles;
       gw += (gridDim.x * 256) >> 6) {
    const int rt = gw / KT, kt = gw % KT;
    const float* src = in + (size_t)(rt * 16 + (l & 15)) * DIMC + kt * 32 + (l >> 4) * 8;
    float4 x0 = *(const float4*)src;
    float4 x1 = *(const float4*)(src + 4);
    float xs[8] = {x0.x, x0.y, x0.z, x0.w, x1.x, x1.y, x1.z, x1.w};
    u32 hw[4], lw[4];
    #pragma unroll
    for (int i = 0; i < 4; ++i) {
      u16 h0 = bf16_rne(xs[2*i]);
      u16 h1 = bf16_rne(xs[2*i+1]);
      float r0 = xs[2*i]   - __uint_as_float(((u32)h0) << 16);
      float r1 = xs[2*i+1] - __uint_as_float(((u32)h1) << 16);
      u16 l0 = bf16_rne(r0);
      u16 l1 = bf16_rne(r1);
      hw[i] = (u32)h0 | ((u32)h1 << 16);
      lw[i] = (u32)l0 | ((u32)l1 << 16);
    }
    u16* tb = outp + (size_t)gw * TILE_U16;
    *(uint4*)(tb + l * 8)       = make_uint4(hw[0], hw[1], hw[2], hw[3]);
    *(uint4*)(tb + 512 + l * 8) = make_uint4(lw[0], lw[1], lw[2], lw[3]);
  }
}

// ---------------------------------------------------------------------------
// Transposed split: source element (row rr, k kk) = in[kk*ld + rr].
// ---------------------------------------------------------------------------
__global__ __launch_bounds__(256)
void split_tiles_t(const float* __restrict__ in, u16* __restrict__ outp,
                   int nrowtiles, int ld) {
  const int l = threadIdx.x & 63;
  const int ntiles = nrowtiles * KT;
  for (int gw = (blockIdx.x * 256 + threadIdx.x) >> 6; gw < ntiles;
       gw += (gridDim.x * 256) >> 6) {
    const int rt = gw / KT, kt = gw % KT;
    const int m = rt * 16 + (l & 15);
    const int k0 = kt * 32 + (l >> 4) * 8;
    float xs[8];
    #pragma unroll
    for (int j = 0; j < 8; ++j) xs[j] = in[(size_t)(k0 + j) * ld + m];
    u32 hw[4], lw[4];
    #pragma unroll
    for (int i = 0; i < 4; ++i) {
      u16 h0 = bf16_rne(xs[2*i]);
      u16 h1 = bf16_rne(xs[2*i+1]);
      float r0 = xs[2*i]   - __uint_as_float(((u32)h0) << 16);
      float r1 = xs[2*i+1] - __uint_as_float(((u32)h1) << 16);
      u16 l0 = bf16_rne(r0);
      u16 l1 = bf16_rne(r1);
      hw[i] = (u32)h0 | ((u32)h1 << 16);
      lw[i] = (u32)l0 | ((u32)l1 << 16);
    }
    u16* tb = outp + (size_t)gw * TILE_U16;
    *(uint4*)(tb + l * 8)       = make_uint4(hw[0], hw[1], hw[2], hw[3]);
    *(uint4*)(tb + 512 + l * 8) = make_uint4(lw[0], lw[1], lw[2], lw[3]);
  }
}

// ---------------------------------------------------------------------------
// Stage 1: qkv GEMM (MFMA bf16x3) + |q|,|k| sums + MFMA kv outer product.
// R18 configuration (best measured).
// ---------------------------------------------------------------------------
__global__ __launch_bounds__(256, 3)
void qkv_stage1(const u16* __restrict__ xc, const u16* __restrict__ wc,
                float* __restrict__ kvp, float* __restrict__ dqp,
                float* __restrict__ dkp) {
  const int bid = blockIdx.x;
  const int h = bid % HEADS;
  const int bc = bid / HEADS;
  const int b = bc >> 3, chunk = bc & 7;
  const int bh = b * HEADS + h;
  const int si = bh * NCHUNK + chunk;

  const int tid = threadIdx.x;
  const int w = tid >> 6, l = tid & 63;
  const int lr16 = l & 15, cg = l >> 4;

  __shared__ __align__(16) unsigned char smem[33792];
  u16* lds16 = (u16*)smem;   // kt loop: A-dbuf 2x4096 u16 at [0,8192)
                             // scatter: k^T tiles [0,8192), v tiles [8192,16384)
  float* red = (float*)smem; // epilogue scratch

  f32x4 kvacc[4] = {(f32x4){0,0,0,0},(f32x4){0,0,0,0},(f32x4){0,0,0,0},(f32x4){0,0,0,0}};
  float dsum_q = 0.f, dsum_k = 0.f;

  const u16* wbase[3];
  #pragma unroll
  for (int ot = 0; ot < 3; ++ot) {
    const int grow = ot * DIMC + h * HD + w * 16;
    wbase[ot] = wc + (size_t)(grow >> 4) * ROWTILE_U16 + (l << 3);
  }
  const int atile0 = (b * SEQ + chunk * CHTOK) >> 4;

  for (int sub = 0; sub < 8; ++sub) {
    const u16* asub = xc + (size_t)(atile0 + sub * 4) * ROWTILE_U16;
    const u16* gw0 = asub + (size_t)w * ROWTILE_U16 + (l << 3);
    __syncthreads();   // prev sub's kv-MFMA reads done -> LDS reusable
    {
      uint4 s0 = *(const uint4*)gw0;
      uint4 s1 = *(const uint4*)(gw0 + 512);
      *(uint4*)(lds16 + w * 1024 + (l << 3))       = s0;
      *(uint4*)(lds16 + w * 1024 + 512 + (l << 3)) = s1;
    }
    __syncthreads();

    f32x4 acc[4][3];
    #pragma unroll
    for (int tt = 0; tt < 4; ++tt)
      #pragma unroll
      for (int ot = 0; ot < 3; ++ot)
        acc[tt][ot] = (f32x4){0.f, 0.f, 0.f, 0.f};

    for (int kt = 0; kt < KT; ++kt) {
      const int cur = (kt & 1) << 12;          // 0 or 4096 u16
      const int nxt = cur ^ 4096;
      uint4 s0, s1;
      if (kt + 1 < KT) {
        const u16* g = gw0 + (kt + 1) * TILE_U16;
        s0 = *(const uint4*)g;
        s1 = *(const uint4*)(g + 512);
      }
      const int off = kt * TILE_U16;
      short8 bh_[3], bl_[3];
      #pragma unroll
      for (int ot = 0; ot < 3; ++ot) {
        bh_[ot] = *(const short8*)(wbase[ot] + off);
        bl_[ot] = *(const short8*)(wbase[ot] + off + 512);
      }
      __builtin_amdgcn_s_setprio(1);
      #pragma unroll
      for (int tt = 0; tt < 4; ++tt) {
        short8 ah = *(const short8*)(lds16 + cur + tt * 1024 + (l << 3));
        short8 al = *(const short8*)(lds16 + cur + tt * 1024 + 512 + (l << 3));
        #pragma unroll
        for (int ot = 0; ot < 3; ++ot) {
          acc[tt][ot] = __builtin_amdgcn_mfma_f32_16x16x32_bf16(ah, bh_[ot], acc[tt][ot], 0, 0, 0);
          acc[tt][ot] = __builtin_amdgcn_mfma_f32_16x16x32_bf16(ah, bl_[ot], acc[tt][ot], 0, 0, 0);
          acc[tt][ot] = __builtin_amdgcn_mfma_f32_16x16x32_bf16(al, bh_[ot], acc[tt][ot], 0, 0, 0);
        }
      }
      __builtin_amdgcn_s_setprio(0);
      if (kt + 1 < KT) {
        *(uint4*)(lds16 + nxt + w * 1024 + (l << 3))       = s0;
        *(uint4*)(lds16 + nxt + w * 1024 + 512 + (l << 3)) = s1;
      }
      __syncthreads();
    }
    // --- scatter phase
    #pragma unroll
    for (int tt = 0; tt < 4; ++tt) {
      dsum_q += fabsf(acc[tt][0][0]);
      dsum_q += fabsf(acc[tt][0][1]);
      dsum_q += fabsf(acc[tt][0][2]);
      dsum_q += fabsf(acc[tt][0][3]);
    }
    #pragma unroll
    for (int sec = 1; sec < 3; ++sec) {
      const int region = (sec == 1) ? 0 : 8192;
      #pragma unroll
      for (int tt = 0; tt < 4; ++tt) {
        const float v0 = acc[tt][sec][0], v1 = acc[tt][sec][1];
        const float v2 = acc[tt][sec][2], v3 = acc[tt][sec][3];
        if (sec == 1) {
          dsum_k += fabsf(v0);
          dsum_k += fabsf(v1);
          dsum_k += fabsf(v2);
          dsum_k += fabsf(v3);
        }
        const u32 ph01 = cvt_pk_bf16(v0, v1);
        const u32 ph23 = cvt_pk_bf16(v2, v3);
        const float r0 = v0 - __uint_as_float(ph01 << 16);
        const float r1 = v1 - __uint_as_float(ph01 & 0xffff0000u);
        const float r2 = v2 - __uint_as_float(ph23 << 16);
        const float r3 = v3 - __uint_as_float(ph23 & 0xffff0000u);
        const u32 pl01 = cvt_pk_bf16(r0, r1);
        const u32 pl23 = cvt_pk_bf16(r2, r3);
        const int pos = region + (w * 2 + (tt >> 1)) * TILE_U16 +
                        ((lr16 | (((tt * 2 + (cg >> 1)) & 3) << 4)) << 3) +
                        ((cg & 1) << 2);
        *(uint2*)(lds16 + pos)       = make_uint2(ph01, ph23);
        *(uint2*)(lds16 + pos + 512) = make_uint2(pl01, pl23);
      }
    }
    __syncthreads();
    // kv MFMA
    {
      const u16* At = lds16 + w * 2 * TILE_U16;
      const u16* Bt = lds16 + 8192;
      __builtin_amdgcn_s_setprio(1);
      #pragma unroll
      for (int t2 = 0; t2 < 2; ++t2) {
        short8 kah = *(const short8*)(At + t2 * TILE_U16 + (l << 3));
        short8 kal = *(const short8*)(At + t2 * TILE_U16 + 512 + (l << 3));
        #pragma unroll
        for (int et = 0; et < 4; ++et) {
          short8 vbh = *(const short8*)(Bt + (et * 2 + t2) * TILE_U16 + (l << 3));
          short8 vbl = *(const short8*)(Bt + (et * 2 + t2) * TILE_U16 + 512 + (l << 3));
          kvacc[et] = __builtin_amdgcn_mfma_f32_16x16x32_bf16(kah, vbh, kvacc[et], 0, 0, 0);
          kvacc[et] = __builtin_amdgcn_mfma_f32_16x16x32_bf16(kah, vbl, kvacc[et], 0, 0, 0);
          kvacc[et] = __builtin_amdgcn_mfma_f32_16x16x32_bf16(kal, vbh, kvacc[et], 0, 0, 0);
        }
      }
      __builtin_amdgcn_s_setprio(0);
    }
  }
  // write kv partial: d = w*16 + cg*4 + r, e = et*16 + lr16
  float* ob = kvp + (size_t)si * (HD * HD);
  #pragma unroll
  for (int et = 0; et < 4; ++et)
    #pragma unroll
    for (int r = 0; r < 4; ++r)
      ob[(w * 16 + cg * 4 + r) * HD + et * 16 + lr16] = kvacc[et][r];
  // dq/dk reduction
  __syncthreads();
  red[(w * 16 + lr16) * 4 + cg]       = dsum_q;
  red[256 + (w * 16 + lr16) * 4 + cg] = dsum_k;
  __syncthreads();
  if (tid < 64) {
    dqp[(size_t)si * HD + tid] = red[tid*4] + red[tid*4+1] + red[tid*4+2] + red[tid*4+3];
  } else if (tid < 128) {
    const int d = tid - 64;
    dkp[(size_t)si * HD + d] = red[256 + d*4] + red[256 + d*4+1] + red[256 + d*4+2] + red[256 + d*4+3];
  }
}

// ---------------------------------------------------------------------------
__global__ __launch_bounds__(256)
void kv_reduce(const float* __restrict__ kvp, const float* __restrict__ dqp,
               const float* __restrict__ dkp, float* __restrict__ kvs) {
  const int bh = blockIdx.x;
  const int tid = threadIdx.x;
  __shared__ float dqL[64], dkL[64];
  if (tid < 64) {
    float s = 0.f;
    #pragma unroll
    for (int c = 0; c < NCHUNK; ++c) s += dqp[((size_t)bh * NCHUNK + c) * HD + tid];
    dqL[tid] = fmaxf(s, EPSN);
  } else if (tid < 128) {
    const int d = tid - 64;
    float s = 0.f;
    #pragma unroll
    for (int c = 0; c < NCHUNK; ++c) s += dkp[((size_t)bh * NCHUNK + c) * HD + d];
    dkL[d] = fmaxf(s, EPSN);
  }
  __syncthreads();
  #pragma unroll
  for (int i = 0; i < 16; ++i) {
    const int idx = i * 256 + tid;
    const int d = idx >> 6;
    float s = 0.f;
    #pragma unroll
    for (int c = 0; c < NCHUNK; ++c)
      s += kvp[((size_t)bh * NCHUNK + c) * (HD * HD) + idx];
    kvs[(size_t)bh * (HD * HD) + idx] = s / (dqL[d] * dkL[d]);
  }
}

// ---------------------------------------------------------------------------
// W2 fused: acc -> bf16 hi/lo -> w2c DIRECTLY in fragment-tile layout
// (row = c = output channel, k = hd). Same bf16_rne on same values as the
// old split_tiles pass -> w2c bit-identical; eliminates a full kernel pass.
// ---------------------------------------------------------------------------
__global__ __launch_bounds__(256)
void w2_kernel(const float* __restrict__ kvs, const float* __restrict__ w_proj,
               u16* __restrict__ w2c) {
  const int bh = blockIdx.x;
  const int b = bh / HEADS, h = bh % HEADS;
  const int c0 = blockIdx.y * 128;
  const int tid = threadIdx.x;
  const int tx = tid & 15, ty = tid >> 4;
  __shared__ float KVe[64][68];
  __shared__ float Wp[64][132];
  #pragma unroll
  for (int i = 0; i < 4; ++i) {
    const int idx = i * 256 + tid;
    const int d  = idx >> 4;
    const int e4 = (idx & 15) << 2;
    float4 v4 = *(const float4*)&kvs[(size_t)bh * (HD*HD) + (size_t)d * HD + e4];
    KVe[e4+0][d] = v4.x; KVe[e4+1][d] = v4.y;
    KVe[e4+2][d] = v4.z; KVe[e4+3][d] = v4.w;
  }
  {
    const int c = tid >> 1, half = tid & 1;
    #pragma unroll
    for (int j = 0; j < 8; ++j) {
      const int e = half * 32 + j * 4;
      float4 v4 = *(const float4*)&w_proj[(size_t)(c0 + c) * DIMC + h * HD + e];
      Wp[e+0][c] = v4.x; Wp[e+1][c] = v4.y; Wp[e+2][c] = v4.z; Wp[e+3][c] = v4.w;
    }
  }
  __syncthreads();
  float acc[4][8] = {};
  for (int e = 0; e < 64; ++e) {
    float4 a4 = *(const float4*)&KVe[e][ty << 2];
    float4 b0 = *(const float4*)&Wp[e][tx << 3];
    float4 b1 = *(const float4*)&Wp[e][(tx << 3) + 4];
    float ar[4] = {a4.x, a4.y, a4.z, a4.w};
    float br[8] = {b0.x,b0.y,b0.z,b0.w,b1.x,b1.y,b1.z,b1.w};
    #pragma unroll
    for (int i = 0; i < 4; ++i)
      #pragma unroll
      for (int j = 0; j < 8; ++j)
        acc[i][j] = fmaf(ar[i], br[j], acc[i][j]);
  }
  // fused split-store: element (row c, k hd) -> tile (b*48 + c/16, hd/32),
  // lane (c&15)|(((hd>>3)&3)<<4), elem hd&7
  #pragma unroll
  for (int j = 0; j < 8; ++j) {
    const int c = c0 + (tx << 3) + j;
    const size_t tb = (size_t)(b * 48 + (c >> 4)) * ROWTILE_U16;
    #pragma unroll
    for (int i = 0; i < 4; ++i) {
      const int hd = h * HD + (ty << 2) + i;
      const float v = acc[i][j];
      const u16 hh = bf16_rne(v);
      const float res = v - __uint_as_float(((u32)hh) << 16);
      const u16 ll = bf16_rne(res);
      u16* p = w2c + tb + (size_t)(hd >> 5) * TILE_U16 +
               (((c & 15) | (((hd >> 3) & 3) << 4)) << 3) + (hd & 7);
      p[0]   = hh;
      p[512] = ll;
    }
  }
}

// ---------------------------------------------------------------------------
// W3T fused: C-fragments -> bf16 hi/lo -> w3c DIRECTLY in fragment-tile
// layout (row = c, k = m). Eliminates the W3T fp32 round-trip + split pass.
// ---------------------------------------------------------------------------
__global__ __launch_bounds__(256)
void w3t_mfma(const u16* __restrict__ w2c, const u16* __restrict__ wqt,
              u16* __restrict__ w3c) {
  const int tid = threadIdx.x;
  const int w = tid >> 6, l = tid & 63;
  const int lr16 = l & 15, cg = l >> 4;
  const int cx = blockIdx.x, my = blockIdx.y, b = blockIdx.z;

  const u16* wbase[3];
  #pragma unroll
  for (int ot = 0; ot < 3; ++ot)
    wbase[ot] = wqt + (size_t)(my * 12 + w * 3 + ot) * ROWTILE_U16 + (l << 3);
  const u16* abase[4];
  #pragma unroll
  for (int tt = 0; tt < 4; ++tt)
    abase[tt] = w2c + (size_t)(b * 48 + cx * 4 + tt) * ROWTILE_U16 + (l << 3);

  f32x4 acc[4][3];
  #pragma unroll
  for (int tt = 0; tt < 4; ++tt)
    #pragma unroll
    for (int ot = 0; ot < 3; ++ot)
      acc[tt][ot] = (f32x4){0.f, 0.f, 0.f, 0.f};

  for (int kt = 0; kt < KT; ++kt) {
    const int off = kt * TILE_U16;
    short8 bh_[3], bl_[3];
    #pragma unroll
    for (int ot = 0; ot < 3; ++ot) {
      bh_[ot] = *(const short8*)(wbase[ot] + off);
      bl_[ot] = *(const short8*)(wbase[ot] + off + 512);
    }
    #pragma unroll
    for (int tt = 0; tt < 4; ++tt) {
      short8 ah = *(const short8*)(abase[tt] + off);
      short8 al = *(const short8*)(abase[tt] + off + 512);
      #pragma unroll
      for (int ot = 0; ot < 3; ++ot) {
        acc[tt][ot] = __builtin_amdgcn_mfma_f32_16x16x32_bf16(ah, bh_[ot], acc[tt][ot], 0, 0, 0);
        acc[tt][ot] = __builtin_amdgcn_mfma_f32_16x16x32_bf16(ah, bl_[ot], acc[tt][ot], 0, 0, 0);
        acc[tt][ot] = __builtin_amdgcn_mfma_f32_16x16x32_bf16(al, bh_[ot], acc[tt][ot], 0, 0, 0);
      }
    }
  }
  // fused split-store: value (row c = cx*64+tt*16+cg*4+r, k m) -> tile
  // (b*48 + c/16, m/32), lane (c&15)|(((m>>3)&3)<<4), elem m&7
  #pragma unroll
  for (int ot = 0; ot < 3; ++ot) {
    const int m = my * 192 + w * 48 + ot * 16 + lr16;
    const size_t koff = (size_t)(m >> 5) * TILE_U16;
    const int kb = (m >> 3) & 3;
    const int elem = m & 7;
    #pragma unroll
    for (int tt = 0; tt < 4; ++tt) {
      const size_t tb = (size_t)(b * 48 + cx * 4 + tt) * ROWTILE_U16 + koff;
      #pragma unroll
      for (int r = 0; r < 4; ++r) {
        const float v = acc[tt][ot][r];
        const u16 hh = bf16_rne(v);
        const float res = v - __uint_as_float(((u32)hh) << 16);
        const u16 ll = bf16_rne(res);
        u16* p = w3c + tb + (((((cg << 2) + r) & 15) | (kb << 4)) << 3) + elem;
        p[0]   = hh;
        p[512] = ll;
      }
    }
  }
}

// ---------------------------------------------------------------------------
// out[b][n][c] = sum_m x[b][n][m] * W3T[b][c][m] + bias[c]
// R18 configuration (A-dbuf + setprio).
// ---------------------------------------------------------------------------
__global__ __launch_bounds__(256, 3)
void final_gemm_mfma(const u16* __restrict__ xc, const u16* __restrict__ w3c,
                     const float* __restrict__ bias, float* __restrict__ out) {
  const int tid = threadIdx.x;
  const int w = tid >> 6, l = tid & 63;
  const int lr16 = l & 15, cg = l >> 4;
  const int ntile = blockIdx.x;
  const int c0 = blockIdx.y * 192;
  const int b = ntile >> 6;
  const int colbase0 = c0 + w * 48;

  __shared__ __align__(16) u16 alds[8192];   // 2 x 4096 u16

  const u16* wbase[3];
  #pragma unroll
  for (int ot = 0; ot < 3; ++ot) {
    const int c = colbase0 + ot * 16;
    wbase[ot] = w3c + (size_t)(b * (DIMC/16) + (c >> 4)) * ROWTILE_U16 + (l << 3);
  }
  const u16* gw0 = xc + (size_t)(ntile * 4 + w) * ROWTILE_U16 + (l << 3);

  {
    uint4 a0 = *(const uint4*)gw0;
    uint4 a1 = *(const uint4*)(gw0 + 512);
    *(uint4*)(alds + w * 1024 + (l << 3))       = a0;
    *(uint4*)(alds + w * 1024 + 512 + (l << 3)) = a1;
  }
  __syncthreads();

  f32x4 acc[4][3];
  #pragma unroll
  for (int tt = 0; tt < 4; ++tt)
    #pragma unroll
    for (int ot = 0; ot < 3; ++ot)
      acc[tt][ot] = (f32x4){0.f, 0.f, 0.f, 0.f};

  for (int kt = 0; kt < KT; ++kt) {
    const int cur = (kt & 1) << 12;
    const int nxt = cur ^ 4096;
    uint4 s0, s1;
    if (kt + 1 < KT) {
      const u16* g = gw0 + (kt + 1) * TILE_U16;
      s0 = *(const uint4*)g;
      s1 = *(const uint4*)(g + 512);
    }
    const int off = kt * TILE_U16;
    short8 bh_[3], bl_[3];
    #pragma unroll
    for (int ot = 0; ot < 3; ++ot) {
      bh_[ot] = *(const short8*)(wbase[ot] + off);
      bl_[ot] = *(const short8*)(wbase[ot] + off + 512);
    }
    __builtin_amdgcn_s_setprio(1);
    #pragma unroll
    for (int tt = 0; tt < 4; ++tt) {
      short8 ah = *(const short8*)(alds + cur + tt * 1024 + (l << 3));
      short8 al = *(const short8*)(alds + cur + tt * 1024 + 512 + (l << 3));
      #pragma unroll
      for (int ot = 0; ot < 3; ++ot) {
        acc[tt][ot] = __builtin_amdgcn_mfma_f32_16x16x32_bf16(ah, bh_[ot], acc[tt][ot], 0, 0, 0);
        acc[tt][ot] = __builtin_amdgcn_mfma_f32_16x16x32_bf16(ah, bl_[ot], acc[tt][ot], 0, 0, 0);
        acc[tt][ot] = __builtin_amdgcn_mfma_f32_16x16x32_bf16(al, bh_[ot], acc[tt][ot], 0, 0, 0);
      }
    }
    __builtin_amdgcn_s_setprio(0);
    if (kt + 1 < KT) {
      *(uint4*)(alds + nxt + w * 1024 + (l << 3))       = s0;
      *(uint4*)(alds + nxt + w * 1024 + 512 + (l << 3)) = s1;
    }
    __syncthreads();
  }
  #pragma unroll
  for (int ot = 0; ot < 3; ++ot) {
    const int col = colbase0 + ot * 16 + lr16;
    const float bv = bias[col];
    #pragma unroll
    for (int tt = 0; tt < 4; ++tt) {
      const size_t row0 = (size_t)ntile * 64 + tt * 16 + cg * 4;
      #pragma unroll
      for (int r = 0; r < 4; ++r)
        out[(row0 + r) * DIMC + col] = acc[tt][ot][r] + bv;
    }
  }
}

// ---------------------------------------------------------------------------
extern "C" void kernel_launch(void* const* d_in, const int* in_sizes, int n_in,
                              void* d_out, int out_size, void* d_ws, size_t ws_size,
                              hipStream_t stream) {
  const float* x      = (const float*)d_in[0];
  const float* w_qkv  = (const float*)d_in[1];
  const float* w_proj = (const float*)d_in[2];
  const float* b_proj = (const float*)d_in[3];
  float* out = (float*)d_out;
  float* ws  = (float*)d_ws;

  // workspace layout (fp32 W2T/W3T intermediates eliminated)
  const size_t KVP_SZ = (size_t)BHN * NCHUNK * HD * HD;
  const size_t DQP_SZ = (size_t)BHN * NCHUNK * HD;
  const size_t KVS_SZ = (size_t)BHN * HD * HD;
  const size_t XC_U16  = (size_t)(MTOK/16) * ROWTILE_U16;
  const size_t WC_U16  = (size_t)(THREEC/16) * ROWTILE_U16;
  const size_t WQT_U16 = (size_t)(DIMC/16) * ROWTILE_U16;
  const size_t W2C_U16 = (size_t)(BATCH*DIMC/16) * ROWTILE_U16;
  const size_t W3C_U16 = (size_t)(BATCH*DIMC/16) * ROWTILE_U16;
  float* kvp  = ws;
  float* dqp  = kvp + KVP_SZ;
  float* dkp  = dqp + DQP_SZ;
  float* kvs  = dkp + DQP_SZ;
  u16*   xc   = (u16*)(kvs + KVS_SZ);
  u16*   wc   = xc + XC_U16;
  u16*   wqt  = wc + WC_U16;
  u16*   w2c  = wqt + WQT_U16;
  u16*   w3c  = w2c + W2C_U16;
  const size_t need_bytes =
      (KVP_SZ + 2*DQP_SZ + KVS_SZ) * sizeof(float) +
      (XC_U16 + WC_U16 + WQT_U16 + W2C_U16 + W3C_U16) * sizeof(u16);
  if (ws_size < need_bytes) return;   // clean validation failure, not a fault

  const dim3 blk(256);
  // 0) split x, w_qkv, w_qkv_q^T into fragment tiles
  split_tiles<<<dim3((MTOK/16) * KT / 4), blk, 0, stream>>>(x, xc, MTOK/16);
  split_tiles<<<dim3((THREEC/16) * KT / 4), blk, 0, stream>>>(w_qkv, wc, THREEC/16);
  split_tiles_t<<<dim3((DIMC/16) * KT / 4), blk, 0, stream>>>(w_qkv, wqt, DIMC/16, DIMC);
  // 1) fused qkv GEMM + |q|,|k| sums + MFMA kv outer product
  qkv_stage1<<<dim3(BHN * NCHUNK), blk, 0, stream>>>(xc, wc, kvp, dqp, dkp);
  // 2) reduce partials + fold denominators
  kv_reduce<<<dim3(BHN), blk, 0, stream>>>(kvp, dqp, dkp, kvs);
  // 3) W2 -> w2c directly (fused split epilogue)
  w2_kernel<<<dim3(BHN, DIMC/128), blk, 0, stream>>>(kvs, w_proj, w2c);
  // 4) W3T = W2T x Wq^T -> w3c directly (fused split epilogue)
  w3t_mfma<<<dim3(DIMC/64, DIMC/192, BATCH), blk, 0, stream>>>(w2c, wqt, w3c);
  // 5) out = x @ W3^T + bias
  final_gemm_mfma<<<dim3(MTOK/64, DIMC/192), blk, 0, stream>>>(xc, w3c, b_proj, out);
}